// Round 10
// baseline (201.158 us; speedup 1.0000x reference)
//
#include <hip/hip_runtime.h>
#include <math.h>

// ---------------------------------------------------------------------------
// Fully fused, zero-array, packed-math kernel.
//
// r7 (G=8, lb(512,1)): headline 119.7us. r8 (G=4, lb(512,2), 2x occupancy +
// 2x per-CU LDS work): headline 119.9us -- Δ=0.2%. Conclusion: kernel is
// small vs the harness reset floor (256MiB d_ws poison ~45us + d_out poison
// + input restore + launch gaps ~= 100+us). This round is the decisive
// probe: halve kernel VALU via v_pk_fma_f32 packing (complex FMA and sign
// FMA are natural 2-wide packed ops). If headline stays ~120, the remaining
// time is harness floor -> declare effective roofline.
//
// Invariants kept: gate math bit-identical to silicon-verified r3/r4/r7/r8
// (absmax 0.0039 vs 0.0185 threshold); NO local arrays (named scalars only,
// rule #20); rolled k-loop only runtime-indexes LDS; no d_ws usage (r2
// post-timing divergence implicated scratch).
// ---------------------------------------------------------------------------

typedef float v2f __attribute__((ext_vector_type(2)));

__device__ inline v2f splat2(float s) { v2f r; r.x = s; r.y = s; return r; }
__device__ inline v2f fma2(v2f a, v2f b, v2f c) { return __builtin_elementwise_fma(a, b, c); }

struct cpx { float r, i; };

__device__ inline cpx cmul(cpx a, cpx b) { return {a.r*b.r - a.i*b.i, a.r*b.i + a.i*b.r}; }
__device__ inline cpx cadd(cpx a, cpx b) { return {a.r + b.r, a.i + b.i}; }

template<int BIT>
__device__ inline void apply2(cpx& x, int j, cpx g00, cpx g01, cpx g10, cpx g11) {
  cpx p;
  p.r = __shfl_xor(x.r, BIT, 64);
  p.i = __shfl_xor(x.i, BIT, 64);
  const bool hi = (j & BIT) != 0;
  const cpx ca = hi ? g11 : g00;
  const cpx cb = hi ? g10 : g01;
  x = cadd(cmul(ca, x), cmul(cb, p));
}

template<int CB, int TB>
__device__ inline void cnotg(cpx& x, int j) {
  cpx p;
  p.r = __shfl_xor(x.r, TB, 64);
  p.i = __shfl_xor(x.i, TB, 64);
  if (j & CB) x = p;
}

template<int BIT>
__device__ inline void u3g(cpx& x, int j, float th, float ph, float lm) {
  float st, ct; __sincosf(0.5f * th, &st, &ct);
  float sp, cp; __sincosf(ph, &sp, &cp);
  float sl, cl; __sincosf(lm, &sl, &cl);
  const cpx g00 = { ct, 0.f };
  const cpx g01 = { -cl * st, -sl * st };
  const cpx g10 = {  cp * st,  sp * st };
  const cpx g11 = { (cp*cl - sp*sl) * ct, (sp*cl + cp*sl) * ct };
  apply2<BIT>(x, j, g00, g01, g10, g11);
}

template<int BIT>
__device__ inline void ryg(cpx& x, int j, float t) {
  float s, c; __sincosf(0.5f * t, &s, &c);
  const float pr = __shfl_xor(x.r, BIT, 64);
  const float pi = __shfl_xor(x.i, BIT, 64);
  const float ss = (j & BIT) ? s : -s;
  x.r = fmaf(ss, pr, c * x.r);
  x.i = fmaf(ss, pi, c * x.i);
}

template<int BIT>
__device__ inline void rzg(cpx& x, int j, float t) {
  float s, c; __sincosf(0.5f * t, &s, &c);
  const float ss = (j & BIT) ? s : -s;
  const float nr = fmaf(-ss, x.i, c * x.r);
  const float ni = fmaf( ss, x.r, c * x.i);
  x.r = nr; x.i = ni;
}

template<int A, int B>
__device__ inline void su4g(cpx& x, int j, const float* const* W) {
  constexpr int BA = 8 >> A, BB = 8 >> B;
  u3g<BA>(x, j, W[0][0], W[0][1], W[0][2]);
  u3g<BB>(x, j, W[1][0], W[1][1], W[1][2]);
  cnotg<BA, BB>(x, j);
  ryg<BA>(x, j, W[2][0]);
  rzg<BB>(x, j, W[3][0]);
  cnotg<BB, BA>(x, j);
  ryg<BA>(x, j, W[4][0]);
  cnotg<BA, BB>(x, j);
  u3g<BA>(x, j, W[5][0], W[5][1], W[5][2]);
  u3g<BB>(x, j, W[6][0], W[6][1], W[6][2]);
}

#define BLK 512
#define G   8
// elements per block = BLK * G = 4096 ; grid = 1048576/4096 = 256 = 1 block/CU

// ---- named-scalar machinery (no arrays -> no scratch, ever) ---------------
#define FORALLG(M) M(0) M(1) M(2) M(3) M(4) M(5) M(6) M(7)
#define FORALLG2(M, jl, jh) M(0,jl,jh) M(1,jl,jh) M(2,jl,jh) M(3,jl,jh) \
                            M(4,jl,jh) M(5,jl,jh) M(6,jl,jh) M(7,jl,jh)

#define DECL_G(g) \
  float ps##g##_0, ps##g##_1, ps##g##_2,  ps##g##_3,  ps##g##_4,  ps##g##_5,  ps##g##_6,  ps##g##_7, \
        ps##g##_8, ps##g##_9, ps##g##_10, ps##g##_11, ps##g##_12, ps##g##_13, ps##g##_14, ps##g##_15; \
  v2f riA##g;                                   /* (re, im) packed          */ \
  v2f acA##g = splat2(0.f), acB##g = splat2(0.f); /* (Z0,Z1) and (Z2,Z3)    */

#define LOAD_G(g) \
  float4 p##g; \
  { const int e = base + g * BLK; \
    p##g = (e < B) ? pat[e] : make_float4(0.f, 0.f, 0.f, 0.f); }

#define INIT_G(g) { \
  const float h0 = HPI * __builtin_amdgcn_rcpf(1.f + __expf(-p##g.x)); \
  const float h1 = HPI * __builtin_amdgcn_rcpf(1.f + __expf(-p##g.y)); \
  const float h2 = HPI * __builtin_amdgcn_rcpf(1.f + __expf(-p##g.z)); \
  const float h3 = HPI * __builtin_amdgcn_rcpf(1.f + __expf(-p##g.w)); \
  float c0,s0,c1,s1,c2,s2,c3,s3; \
  __sincosf(h0, &s0, &c0); __sincosf(h1, &s1, &c1); \
  __sincosf(h2, &s2, &c2); __sincosf(h3, &s3, &c3); \
  const float a0 = c0*c1, a1 = c0*s1, a2 = s0*c1, a3 = s0*s1; \
  const float b0 = c2*c3, b1 = c2*s3, b2 = s2*c3, b3 = s2*s3; \
  ps##g##_0  = a0*b0; ps##g##_1  = a0*b1; ps##g##_2  = a0*b2; ps##g##_3  = a0*b3; \
  ps##g##_4  = a1*b0; ps##g##_5  = a1*b1; ps##g##_6  = a1*b2; ps##g##_7  = a1*b3; \
  ps##g##_8  = a2*b0; ps##g##_9  = a2*b1; ps##g##_10 = a2*b2; ps##g##_11 = a2*b3; \
  ps##g##_12 = a3*b0; ps##g##_13 = a3*b1; ps##g##_14 = a3*b2; ps##g##_15 = a3*b3; }

// first chunk: multiply (initializes riA, no zero-init)
#define MUL4(g, jl, jh) \
  riA##g = qa * splat2(ps##g##_##jl); \
  riA##g = fma2(qb, splat2(ps##g##_##jh), riA##g);
// subsequent chunks: accumulate (packed complex FMA -> v_pk_fma_f32)
#define FMA4(g, jl, jh) \
  riA##g = fma2(qa, splat2(ps##g##_##jl), riA##g); \
  riA##g = fma2(qb, splat2(ps##g##_##jh), riA##g);

#define STEP(j2, jl, jh, MM) { \
  const float4 q = rowp[j2]; \
  v2f qa; qa.x = q.x; qa.y = q.y; \
  v2f qb; qb.x = q.z; qb.y = q.w; \
  FORALLG2(MM, jl, jh) }

#define ACC_G(g) { \
  const float pr = fmaf(riA##g.x, riA##g.x, riA##g.y * riA##g.y); \
  acA##g = fma2(sA, splat2(pr), acA##g); \
  acB##g = fma2(sB, splat2(pr), acB##g); }

#define STORE_G(g) { \
  const int e = base + g * BLK; \
  if (e < B) out[e] = make_float4(acA##g.x, acA##g.y, acB##g.x, acB##g.y); }

__global__ __launch_bounds__(BLK, 1)
void quanv_fused(const float4* __restrict__ pat,
                 const float* w0,  const float* w1,  const float* w2,
                 const float* w3,  const float* w4,  const float* w5,
                 const float* w6,  const float* w7,  const float* w8,
                 const float* w9,  const float* w10, const float* w11,
                 const float* w12, const float* w13,
                 float4* __restrict__ out, int B) {
  __shared__ float4 Ush4[128];   // ((float2*)Ush4)[k*16+j] = U[k][j]

  const int tid  = threadIdx.x;
  const int base = blockIdx.x * (BLK * G) + tid;
  const float HPI = 1.5707963267948966f;  // pi/2

  // ---- issue patch loads early (HBM latency hides under the build) ----
  FORALLG(LOAD_G)

  // ---- in-block unitary build: threads 0..255, silicon-verified ----
  if (tid < 256) {
    const int col = tid >> 4;
    const int j   = tid & 15;
    cpx x = { (j == col) ? 1.f : 0.f, 0.f };
    {
      const float* WA[7] = { w0, w1, w2, w3, w4, w5, w6 };
      su4g<0,1>(x, j, WA); su4g<1,2>(x, j, WA);
      su4g<2,3>(x, j, WA); su4g<3,0>(x, j, WA);
    }
    {
      const float* WB[7] = { w7, w8, w9, w10, w11, w12, w13 };
      su4g<0,1>(x, j, WB); su4g<1,2>(x, j, WB);
      su4g<2,3>(x, j, WB); su4g<3,0>(x, j, WB);
    }
    ((float2*)Ush4)[j * 16 + col] = make_float2(x.r, x.i);
  }
  __syncthreads();

  // ---- psi0 = product state (named scalars) ----
  FORALLG(DECL_G)
  FORALLG(INIT_G)

  // ---- 16 k-rows: |<k|U|psi0>|^2 with packed Z-sign accumulation ----
  for (int k = 0; k < 16; ++k) {
    const float4* __restrict__ rowp = &Ush4[k * 8];   // row k = 8 float4
    v2f sA; sA.x = (k & 8) ? -1.f : 1.f; sA.y = (k & 4) ? -1.f : 1.f;
    v2f sB; sB.x = (k & 2) ? -1.f : 1.f; sB.y = (k & 1) ? -1.f : 1.f;
    STEP(0,  0,  1, MUL4)
    STEP(1,  2,  3, FMA4)
    STEP(2,  4,  5, FMA4)
    STEP(3,  6,  7, FMA4)
    STEP(4,  8,  9, FMA4)
    STEP(5, 10, 11, FMA4)
    STEP(6, 12, 13, FMA4)
    STEP(7, 14, 15, FMA4)
    FORALLG(ACC_G)
  }

  FORALLG(STORE_G)
}

// ---------------------------------------------------------------------------
extern "C" void kernel_launch(void* const* d_in, const int* in_sizes, int n_in,
                              void* d_out, int out_size, void* d_ws, size_t ws_size,
                              hipStream_t stream) {
  (void)n_in; (void)out_size; (void)d_ws; (void)ws_size;
  const int B = in_sizes[0] / 4;
  const int blocks = (B + BLK * G - 1) / (BLK * G);
  quanv_fused<<<blocks, BLK, 0, stream>>>(
      (const float4*)d_in[0],
      (const float*)d_in[1],  (const float*)d_in[2],  (const float*)d_in[3],
      (const float*)d_in[4],  (const float*)d_in[5],  (const float*)d_in[6],
      (const float*)d_in[7],  (const float*)d_in[8],  (const float*)d_in[9],
      (const float*)d_in[10], (const float*)d_in[11], (const float*)d_in[12],
      (const float*)d_in[13], (const float*)d_in[14],
      (float4*)d_out, B);
}

// Round 11
// 143.663 us; speedup vs baseline: 1.4002x; 1.4002x over previous
//
#include <hip/hip_runtime.h>
#include <math.h>

// ---------------------------------------------------------------------------
// DIAGNOSTIC ROUND: exact r7 kernel (best measured: headline 119.7us,
// kernel <43us), launched TWICE so the kernel lands in rocprof's top-5
// (it hides below the ~45us harness fills otherwise). Second launch writes
// bit-identical values -> deterministic, graph-safe, tripwire-safe.
//
// r10 lesson: v2f ext_vector packing -> even-aligned VGPR pairs fragmented
// regalloc -> allocator chose 128 VGPR + spill (FETCH 39/WRITE 53 MiB) ->
// kernel 121us (3x regression). Scalar-only code is the proven structure.
//
// Invariants: gate math bit-identical to silicon-verified r3/r4/r7/r8/r10
// (absmax 0.0039); NO local arrays (named scalars, rule #20); rolled k-loop
// only runtime-indexes LDS; no d_ws usage.
// ---------------------------------------------------------------------------

struct cpx { float r, i; };

__device__ inline cpx cmul(cpx a, cpx b) { return {a.r*b.r - a.i*b.i, a.r*b.i + a.i*b.r}; }
__device__ inline cpx cadd(cpx a, cpx b) { return {a.r + b.r, a.i + b.i}; }

template<int BIT>
__device__ inline void apply2(cpx& x, int j, cpx g00, cpx g01, cpx g10, cpx g11) {
  cpx p;
  p.r = __shfl_xor(x.r, BIT, 64);
  p.i = __shfl_xor(x.i, BIT, 64);
  const bool hi = (j & BIT) != 0;
  const cpx ca = hi ? g11 : g00;
  const cpx cb = hi ? g10 : g01;
  x = cadd(cmul(ca, x), cmul(cb, p));
}

template<int CB, int TB>
__device__ inline void cnotg(cpx& x, int j) {
  cpx p;
  p.r = __shfl_xor(x.r, TB, 64);
  p.i = __shfl_xor(x.i, TB, 64);
  if (j & CB) x = p;
}

template<int BIT>
__device__ inline void u3g(cpx& x, int j, float th, float ph, float lm) {
  float st, ct; __sincosf(0.5f * th, &st, &ct);
  float sp, cp; __sincosf(ph, &sp, &cp);
  float sl, cl; __sincosf(lm, &sl, &cl);
  const cpx g00 = { ct, 0.f };
  const cpx g01 = { -cl * st, -sl * st };
  const cpx g10 = {  cp * st,  sp * st };
  const cpx g11 = { (cp*cl - sp*sl) * ct, (sp*cl + cp*sl) * ct };
  apply2<BIT>(x, j, g00, g01, g10, g11);
}

template<int BIT>
__device__ inline void ryg(cpx& x, int j, float t) {
  float s, c; __sincosf(0.5f * t, &s, &c);
  const float pr = __shfl_xor(x.r, BIT, 64);
  const float pi = __shfl_xor(x.i, BIT, 64);
  const float ss = (j & BIT) ? s : -s;
  x.r = fmaf(ss, pr, c * x.r);
  x.i = fmaf(ss, pi, c * x.i);
}

template<int BIT>
__device__ inline void rzg(cpx& x, int j, float t) {
  float s, c; __sincosf(0.5f * t, &s, &c);
  const float ss = (j & BIT) ? s : -s;
  const float nr = fmaf(-ss, x.i, c * x.r);
  const float ni = fmaf( ss, x.r, c * x.i);
  x.r = nr; x.i = ni;
}

template<int A, int B>
__device__ inline void su4g(cpx& x, int j, const float* const* W) {
  constexpr int BA = 8 >> A, BB = 8 >> B;
  u3g<BA>(x, j, W[0][0], W[0][1], W[0][2]);
  u3g<BB>(x, j, W[1][0], W[1][1], W[1][2]);
  cnotg<BA, BB>(x, j);
  ryg<BA>(x, j, W[2][0]);
  rzg<BB>(x, j, W[3][0]);
  cnotg<BB, BA>(x, j);
  ryg<BA>(x, j, W[4][0]);
  cnotg<BA, BB>(x, j);
  u3g<BA>(x, j, W[5][0], W[5][1], W[5][2]);
  u3g<BB>(x, j, W[6][0], W[6][1], W[6][2]);
}

#define BLK 512
#define G   8
// elements per block = BLK * G = 4096 ; grid = 1048576/4096 = 256 = 1 block/CU

// ---- named-scalar machinery (no arrays -> no scratch, ever) ---------------
#define FORALLG(M) M(0) M(1) M(2) M(3) M(4) M(5) M(6) M(7)
#define FORALLG2(M, jl, jh) M(0,jl,jh) M(1,jl,jh) M(2,jl,jh) M(3,jl,jh) \
                            M(4,jl,jh) M(5,jl,jh) M(6,jl,jh) M(7,jl,jh)

#define DECL_G(g) \
  float ps##g##_0, ps##g##_1, ps##g##_2,  ps##g##_3,  ps##g##_4,  ps##g##_5,  ps##g##_6,  ps##g##_7, \
        ps##g##_8, ps##g##_9, ps##g##_10, ps##g##_11, ps##g##_12, ps##g##_13, ps##g##_14, ps##g##_15; \
  float ax##g = 0.f, ay##g = 0.f, az##g = 0.f, aw##g = 0.f; \
  float re##g, im##g;

#define LOAD_G(g) \
  float4 p##g; \
  { const int e = base + g * BLK; \
    p##g = (e < B) ? pat[e] : make_float4(0.f, 0.f, 0.f, 0.f); }

#define INIT_G(g) { \
  const float h0 = HPI * __builtin_amdgcn_rcpf(1.f + __expf(-p##g.x)); \
  const float h1 = HPI * __builtin_amdgcn_rcpf(1.f + __expf(-p##g.y)); \
  const float h2 = HPI * __builtin_amdgcn_rcpf(1.f + __expf(-p##g.z)); \
  const float h3 = HPI * __builtin_amdgcn_rcpf(1.f + __expf(-p##g.w)); \
  float c0,s0,c1,s1,c2,s2,c3,s3; \
  __sincosf(h0, &s0, &c0); __sincosf(h1, &s1, &c1); \
  __sincosf(h2, &s2, &c2); __sincosf(h3, &s3, &c3); \
  const float a0 = c0*c1, a1 = c0*s1, a2 = s0*c1, a3 = s0*s1; \
  const float b0 = c2*c3, b1 = c2*s3, b2 = s2*c3, b3 = s2*s3; \
  ps##g##_0  = a0*b0; ps##g##_1  = a0*b1; ps##g##_2  = a0*b2; ps##g##_3  = a0*b3; \
  ps##g##_4  = a1*b0; ps##g##_5  = a1*b1; ps##g##_6  = a1*b2; ps##g##_7  = a1*b3; \
  ps##g##_8  = a2*b0; ps##g##_9  = a2*b1; ps##g##_10 = a2*b2; ps##g##_11 = a2*b3; \
  ps##g##_12 = a3*b0; ps##g##_13 = a3*b1; ps##g##_14 = a3*b2; ps##g##_15 = a3*b3; }

// first chunk: multiply (initializes re/im, no zero-init movs)
#define MUL4(g, jl, jh) \
  re##g = qx * ps##g##_##jl;            im##g = qy * ps##g##_##jl; \
  re##g = fmaf(qz, ps##g##_##jh, re##g); im##g = fmaf(qw, ps##g##_##jh, im##g);
// subsequent chunks: accumulate
#define FMA4(g, jl, jh) \
  re##g = fmaf(qx, ps##g##_##jl, re##g); im##g = fmaf(qy, ps##g##_##jl, im##g); \
  re##g = fmaf(qz, ps##g##_##jh, re##g); im##g = fmaf(qw, ps##g##_##jh, im##g);

#define STEP(j2, jl, jh, MM) { \
  const float4 q = rowp[j2]; \
  const float qx = q.x, qy = q.y, qz = q.z, qw = q.w; \
  FORALLG2(MM, jl, jh) }

#define ACC_G(g) { \
  const float pr = fmaf(re##g, re##g, im##g * im##g); \
  ax##g = fmaf(s8, pr, ax##g); ay##g = fmaf(s4, pr, ay##g); \
  az##g = fmaf(s2, pr, az##g); aw##g = fmaf(s1, pr, aw##g); }

#define STORE_G(g) { \
  const int e = base + g * BLK; \
  if (e < B) out[e] = make_float4(ax##g, ay##g, az##g, aw##g); }

__global__ __launch_bounds__(BLK, 1)
void quanv_fused(const float4* __restrict__ pat,
                 const float* w0,  const float* w1,  const float* w2,
                 const float* w3,  const float* w4,  const float* w5,
                 const float* w6,  const float* w7,  const float* w8,
                 const float* w9,  const float* w10, const float* w11,
                 const float* w12, const float* w13,
                 float4* __restrict__ out, int B) {
  __shared__ float4 Ush4[128];   // ((float2*)Ush4)[k*16+j] = U[k][j]

  const int tid  = threadIdx.x;
  const int base = blockIdx.x * (BLK * G) + tid;
  const float HPI = 1.5707963267948966f;  // pi/2

  // ---- issue patch loads early (HBM latency hides under the build) ----
  FORALLG(LOAD_G)

  // ---- in-block unitary build: threads 0..255, silicon-verified ----
  if (tid < 256) {
    const int col = tid >> 4;
    const int j   = tid & 15;
    cpx x = { (j == col) ? 1.f : 0.f, 0.f };
    {
      const float* WA[7] = { w0, w1, w2, w3, w4, w5, w6 };
      su4g<0,1>(x, j, WA); su4g<1,2>(x, j, WA);
      su4g<2,3>(x, j, WA); su4g<3,0>(x, j, WA);
    }
    {
      const float* WB[7] = { w7, w8, w9, w10, w11, w12, w13 };
      su4g<0,1>(x, j, WB); su4g<1,2>(x, j, WB);
      su4g<2,3>(x, j, WB); su4g<3,0>(x, j, WB);
    }
    ((float2*)Ush4)[j * 16 + col] = make_float2(x.r, x.i);
  }
  __syncthreads();

  // ---- psi0 = product state (named scalars) ----
  FORALLG(DECL_G)
  FORALLG(INIT_G)

  // ---- 16 k-rows: |<k|U|psi0>|^2 with Z-sign accumulation ----
  for (int k = 0; k < 16; ++k) {
    const float4* __restrict__ rowp = &Ush4[k * 8];   // row k = 8 float4
    const float s8 = (k & 8) ? -1.f : 1.f;
    const float s4 = (k & 4) ? -1.f : 1.f;
    const float s2 = (k & 2) ? -1.f : 1.f;
    const float s1 = (k & 1) ? -1.f : 1.f;
    STEP(0,  0,  1, MUL4)
    STEP(1,  2,  3, FMA4)
    STEP(2,  4,  5, FMA4)
    STEP(3,  6,  7, FMA4)
    STEP(4,  8,  9, FMA4)
    STEP(5, 10, 11, FMA4)
    STEP(6, 12, 13, FMA4)
    STEP(7, 14, 15, FMA4)
    FORALLG(ACC_G)
  }

  FORALLG(STORE_G)
}

// ---------------------------------------------------------------------------
extern "C" void kernel_launch(void* const* d_in, const int* in_sizes, int n_in,
                              void* d_out, int out_size, void* d_ws, size_t ws_size,
                              hipStream_t stream) {
  (void)n_in; (void)out_size; (void)d_ws; (void)ws_size;
  const int B = in_sizes[0] / 4;
  const int blocks = (B + BLK * G - 1) / (BLK * G);
  // Launch TWICE (diagnostic): forces the kernel into rocprof top-5 so we
  // get its VGPR/FETCH/WRITE/VALUBusy counters. Second launch recomputes
  // bit-identical outputs -> same work every call, graph/tripwire-safe.
  for (int rep = 0; rep < 2; ++rep) {
    quanv_fused<<<blocks, BLK, 0, stream>>>(
        (const float4*)d_in[0],
        (const float*)d_in[1],  (const float*)d_in[2],  (const float*)d_in[3],
        (const float*)d_in[4],  (const float*)d_in[5],  (const float*)d_in[6],
        (const float*)d_in[7],  (const float*)d_in[8],  (const float*)d_in[9],
        (const float*)d_in[10], (const float*)d_in[11], (const float*)d_in[12],
        (const float*)d_in[13], (const float*)d_in[14],
        (float4*)d_out, B);
  }
}

// Round 12
// 118.745 us; speedup vs baseline: 1.6940x; 1.2098x over previous
//
#include <hip/hip_runtime.h>
#include <math.h>

// ---------------------------------------------------------------------------
// Fully fused, zero-array kernel — build-split edition.
//
// Accounting (r7/r11): headline 119.7us = harness floor ~96us (256MiB d_ws
// poison ~45us @6TB/s + d_out poison + d_in restore + launch gaps) + kernel
// ~24us (measured via r11 dup-launch delta: 143.7-119.7). Kernel model:
// bulk VALU ~9us, LDS ~5us (overlapped), serial 80-gate build ~5-6us.
// r12 change: halve the build's serial chain. U = L2*L1: threads 0-255
// evolve layer-1 columns, threads 256-511 layer-2 columns CONCURRENTLY
// (40 gates each instead of 80 serial), then 256 threads do the 16x16
// complex matmul from LDS. Bulk path bit-identical to r7's verified code.
//
// r10 lesson kept: no ext_vector packing (fragments regalloc -> 128-cap +
// spill). Rule #20 kept: no local arrays; k-loop only runtime-indexes LDS.
// No d_ws (r2 post-timing divergence). Single launch (r11's dup removed).
// ---------------------------------------------------------------------------

struct cpx { float r, i; };

__device__ inline cpx cmul(cpx a, cpx b) { return {a.r*b.r - a.i*b.i, a.r*b.i + a.i*b.r}; }
__device__ inline cpx cadd(cpx a, cpx b) { return {a.r + b.r, a.i + b.i}; }

template<int BIT>
__device__ inline void apply2(cpx& x, int j, cpx g00, cpx g01, cpx g10, cpx g11) {
  cpx p;
  p.r = __shfl_xor(x.r, BIT, 64);
  p.i = __shfl_xor(x.i, BIT, 64);
  const bool hi = (j & BIT) != 0;
  const cpx ca = hi ? g11 : g00;
  const cpx cb = hi ? g10 : g01;
  x = cadd(cmul(ca, x), cmul(cb, p));
}

template<int CB, int TB>
__device__ inline void cnotg(cpx& x, int j) {
  cpx p;
  p.r = __shfl_xor(x.r, TB, 64);
  p.i = __shfl_xor(x.i, TB, 64);
  if (j & CB) x = p;
}

template<int BIT>
__device__ inline void u3g(cpx& x, int j, float th, float ph, float lm) {
  float st, ct; __sincosf(0.5f * th, &st, &ct);
  float sp, cp; __sincosf(ph, &sp, &cp);
  float sl, cl; __sincosf(lm, &sl, &cl);
  const cpx g00 = { ct, 0.f };
  const cpx g01 = { -cl * st, -sl * st };
  const cpx g10 = {  cp * st,  sp * st };
  const cpx g11 = { (cp*cl - sp*sl) * ct, (sp*cl + cp*sl) * ct };
  apply2<BIT>(x, j, g00, g01, g10, g11);
}

template<int BIT>
__device__ inline void ryg(cpx& x, int j, float t) {
  float s, c; __sincosf(0.5f * t, &s, &c);
  const float pr = __shfl_xor(x.r, BIT, 64);
  const float pi = __shfl_xor(x.i, BIT, 64);
  const float ss = (j & BIT) ? s : -s;
  x.r = fmaf(ss, pr, c * x.r);
  x.i = fmaf(ss, pi, c * x.i);
}

template<int BIT>
__device__ inline void rzg(cpx& x, int j, float t) {
  float s, c; __sincosf(0.5f * t, &s, &c);
  const float ss = (j & BIT) ? s : -s;
  const float nr = fmaf(-ss, x.i, c * x.r);
  const float ni = fmaf( ss, x.r, c * x.i);
  x.r = nr; x.i = ni;
}

template<int A, int B>
__device__ inline void su4g(cpx& x, int j, const float* const* W) {
  constexpr int BA = 8 >> A, BB = 8 >> B;
  u3g<BA>(x, j, W[0][0], W[0][1], W[0][2]);
  u3g<BB>(x, j, W[1][0], W[1][1], W[1][2]);
  cnotg<BA, BB>(x, j);
  ryg<BA>(x, j, W[2][0]);
  rzg<BB>(x, j, W[3][0]);
  cnotg<BB, BA>(x, j);
  ryg<BA>(x, j, W[4][0]);
  cnotg<BA, BB>(x, j);
  u3g<BA>(x, j, W[5][0], W[5][1], W[5][2]);
  u3g<BB>(x, j, W[6][0], W[6][1], W[6][2]);
}

#define BLK 512
#define G   8
// elements per block = BLK * G = 4096 ; grid = 1048576/4096 = 256 = 1 block/CU

// ---- named-scalar machinery (no arrays -> no scratch, ever) ---------------
#define FORALLG(M) M(0) M(1) M(2) M(3) M(4) M(5) M(6) M(7)
#define FORALLG2(M, jl, jh) M(0,jl,jh) M(1,jl,jh) M(2,jl,jh) M(3,jl,jh) \
                            M(4,jl,jh) M(5,jl,jh) M(6,jl,jh) M(7,jl,jh)

#define DECL_G(g) \
  float ps##g##_0, ps##g##_1, ps##g##_2,  ps##g##_3,  ps##g##_4,  ps##g##_5,  ps##g##_6,  ps##g##_7, \
        ps##g##_8, ps##g##_9, ps##g##_10, ps##g##_11, ps##g##_12, ps##g##_13, ps##g##_14, ps##g##_15; \
  float ax##g = 0.f, ay##g = 0.f, az##g = 0.f, aw##g = 0.f; \
  float re##g, im##g;

#define LOAD_G(g) \
  float4 p##g; \
  { const int e = base + g * BLK; \
    p##g = (e < B) ? pat[e] : make_float4(0.f, 0.f, 0.f, 0.f); }

#define INIT_G(g) { \
  const float h0 = HPI * __builtin_amdgcn_rcpf(1.f + __expf(-p##g.x)); \
  const float h1 = HPI * __builtin_amdgcn_rcpf(1.f + __expf(-p##g.y)); \
  const float h2 = HPI * __builtin_amdgcn_rcpf(1.f + __expf(-p##g.z)); \
  const float h3 = HPI * __builtin_amdgcn_rcpf(1.f + __expf(-p##g.w)); \
  float c0,s0,c1,s1,c2,s2,c3,s3; \
  __sincosf(h0, &s0, &c0); __sincosf(h1, &s1, &c1); \
  __sincosf(h2, &s2, &c2); __sincosf(h3, &s3, &c3); \
  const float a0 = c0*c1, a1 = c0*s1, a2 = s0*c1, a3 = s0*s1; \
  const float b0 = c2*c3, b1 = c2*s3, b2 = s2*c3, b3 = s2*s3; \
  ps##g##_0  = a0*b0; ps##g##_1  = a0*b1; ps##g##_2  = a0*b2; ps##g##_3  = a0*b3; \
  ps##g##_4  = a1*b0; ps##g##_5  = a1*b1; ps##g##_6  = a1*b2; ps##g##_7  = a1*b3; \
  ps##g##_8  = a2*b0; ps##g##_9  = a2*b1; ps##g##_10 = a2*b2; ps##g##_11 = a2*b3; \
  ps##g##_12 = a3*b0; ps##g##_13 = a3*b1; ps##g##_14 = a3*b2; ps##g##_15 = a3*b3; }

// first chunk: multiply (initializes re/im, no zero-init movs)
#define MUL4(g, jl, jh) \
  re##g = qx * ps##g##_##jl;            im##g = qy * ps##g##_##jl; \
  re##g = fmaf(qz, ps##g##_##jh, re##g); im##g = fmaf(qw, ps##g##_##jh, im##g);
// subsequent chunks: accumulate
#define FMA4(g, jl, jh) \
  re##g = fmaf(qx, ps##g##_##jl, re##g); im##g = fmaf(qy, ps##g##_##jl, im##g); \
  re##g = fmaf(qz, ps##g##_##jh, re##g); im##g = fmaf(qw, ps##g##_##jh, im##g);

#define STEP(j2, jl, jh, MM) { \
  const float4 q = rowp[j2]; \
  const float qx = q.x, qy = q.y, qz = q.z, qw = q.w; \
  FORALLG2(MM, jl, jh) }

#define ACC_G(g) { \
  const float pr = fmaf(re##g, re##g, im##g * im##g); \
  ax##g = fmaf(s8, pr, ax##g); ay##g = fmaf(s4, pr, ay##g); \
  az##g = fmaf(s2, pr, az##g); aw##g = fmaf(s1, pr, aw##g); }

#define STORE_G(g) { \
  const int e = base + g * BLK; \
  if (e < B) out[e] = make_float4(ax##g, ay##g, az##g, aw##g); }

__global__ __launch_bounds__(BLK, 1)
void quanv_fused(const float4* __restrict__ pat,
                 const float* w0,  const float* w1,  const float* w2,
                 const float* w3,  const float* w4,  const float* w5,
                 const float* w6,  const float* w7,  const float* w8,
                 const float* w9,  const float* w10, const float* w11,
                 const float* w12, const float* w13,
                 float4* __restrict__ out, int B) {
  __shared__ float2 L1sh[256];   // L1sh[m*16+c] = layer1[m][c]
  __shared__ float2 L2sh[256];   // L2sh[k*16+m] = layer2[k][m]
  __shared__ float4 Ush4[128];   // ((float2*)Ush4)[k*16+c] = U[k][c]

  const int tid  = threadIdx.x;
  const int base = blockIdx.x * (BLK * G) + tid;
  const float HPI = 1.5707963267948966f;  // pi/2

  // ---- issue patch loads early (HBM latency hides under the build) ----
  FORALLG(LOAD_G)

  // ---- build, split into two concurrent 40-gate halves ----
  // threads 0..255: layer 1 columns; threads 256..511: layer 2 columns.
  {
    const int col = (tid & 255) >> 4;
    const int j   = tid & 15;
    cpx x = { (j == col) ? 1.f : 0.f, 0.f };
    if (tid < 256) {
      const float* W[7] = { w0, w1, w2, w3, w4, w5, w6 };
      su4g<0,1>(x, j, W); su4g<1,2>(x, j, W);
      su4g<2,3>(x, j, W); su4g<3,0>(x, j, W);
      L1sh[j * 16 + col] = make_float2(x.r, x.i);   // row j, column col
    } else {
      const float* W[7] = { w7, w8, w9, w10, w11, w12, w13 };
      su4g<0,1>(x, j, W); su4g<1,2>(x, j, W);
      su4g<2,3>(x, j, W); su4g<3,0>(x, j, W);
      L2sh[j * 16 + col] = make_float2(x.r, x.i);
    }
  }

  // ---- psi0 = product state (named scalars) — all threads, overlaps
  //      nothing serial but is out of the post-barrier critical path ----
  FORALLG(DECL_G)
  FORALLG(INIT_G)

  __syncthreads();

  // ---- U = L2 * L1 : 256 threads, one entry each (16 complex FMA) ----
  if (tid < 256) {
    const int k = tid >> 4, c = tid & 15;
    float ar = 0.f, ai = 0.f;
#pragma unroll
    for (int m = 0; m < 16; ++m) {
      const float2 a = L2sh[k * 16 + m];   // L2[k][m]
      const float2 b = L1sh[m * 16 + c];   // L1[m][c]
      ar = fmaf(a.x, b.x, fmaf(-a.y, b.y, ar));
      ai = fmaf(a.x, b.y, fmaf( a.y, b.x, ai));
    }
    ((float2*)Ush4)[k * 16 + c] = make_float2(ar, ai);
  }
  __syncthreads();

  // ---- 16 k-rows: |<k|U|psi0>|^2 with Z-sign accumulation (r7 verified) ----
  for (int k = 0; k < 16; ++k) {
    const float4* __restrict__ rowp = &Ush4[k * 8];   // row k = 8 float4
    const float s8 = (k & 8) ? -1.f : 1.f;
    const float s4 = (k & 4) ? -1.f : 1.f;
    const float s2 = (k & 2) ? -1.f : 1.f;
    const float s1 = (k & 1) ? -1.f : 1.f;
    STEP(0,  0,  1, MUL4)
    STEP(1,  2,  3, FMA4)
    STEP(2,  4,  5, FMA4)
    STEP(3,  6,  7, FMA4)
    STEP(4,  8,  9, FMA4)
    STEP(5, 10, 11, FMA4)
    STEP(6, 12, 13, FMA4)
    STEP(7, 14, 15, FMA4)
    FORALLG(ACC_G)
  }

  FORALLG(STORE_G)
}

// ---------------------------------------------------------------------------
extern "C" void kernel_launch(void* const* d_in, const int* in_sizes, int n_in,
                              void* d_out, int out_size, void* d_ws, size_t ws_size,
                              hipStream_t stream) {
  (void)n_in; (void)out_size; (void)d_ws; (void)ws_size;
  const int B = in_sizes[0] / 4;
  const int blocks = (B + BLK * G - 1) / (BLK * G);
  quanv_fused<<<blocks, BLK, 0, stream>>>(
      (const float4*)d_in[0],
      (const float*)d_in[1],  (const float*)d_in[2],  (const float*)d_in[3],
      (const float*)d_in[4],  (const float*)d_in[5],  (const float*)d_in[6],
      (const float*)d_in[7],  (const float*)d_in[8],  (const float*)d_in[9],
      (const float*)d_in[10], (const float*)d_in[11], (const float*)d_in[12],
      (const float*)d_in[13], (const float*)d_in[14],
      (float4*)d_out, B);
}